// Round 16
// baseline (566.735 us; speedup 1.0000x reference)
//
#include <hip/hip_runtime.h>
#include <stdint.h>

#define B_DIM 8192
#define DIN   2048
#define DOUT  8192
#define NKT   (DIN / 128)  // 16 K-tiles of 128 bytes

typedef int  v4i __attribute__((ext_vector_type(4)));
typedef char c8  __attribute__((ext_vector_type(8)));

__device__ __forceinline__ void gload_lds16(const void* g, void* l) {
  __builtin_amdgcn_global_load_lds(
      (const __attribute__((address_space(1))) void*)g,
      (__attribute__((address_space(3))) void*)l, 16, 0, 0);
}

__device__ __forceinline__ float wave_max(float m) {
#pragma unroll
  for (int off = 32; off; off >>= 1) m = fmaxf(m, __shfl_xor(m, off, 64));
  return m;
}

// ---- kernel 0: zero the two atomic absmax words ----
__global__ void k_init(unsigned int* p) {
  p[0] = 0u;
  p[1] = 0u;
}

// ---- kernel 1: global absmax of x (block-reduced, 1 atomic/block) ----
__global__ __launch_bounds__(256) void k_absmax(const float4* __restrict__ x,
                                                int n4,
                                                unsigned int* __restrict__ out_bits) {
  int idx = blockIdx.x * blockDim.x + threadIdx.x;
  int stride = gridDim.x * blockDim.x;
  float m = 0.f;
  for (int i = idx; i < n4; i += stride) {
    float4 v = x[i];
    m = fmaxf(m, fabsf(v.x));
    m = fmaxf(m, fabsf(v.y));
    m = fmaxf(m, fabsf(v.z));
    m = fmaxf(m, fabsf(v.w));
  }
  m = wave_max(m);
  __shared__ float red[4];
  if ((threadIdx.x & 63) == 0) red[threadIdx.x >> 6] = m;
  __syncthreads();
  if (threadIdx.x == 0) {
    m = fmaxf(fmaxf(red[0], red[1]), fmaxf(red[2], red[3]));
    atomicMax(out_bits, __float_as_uint(m));
  }
}

// ---- kernel 2: quantize x to int8 (8 elems/thread) ----
__global__ void k_quant_x(const float* __restrict__ x, c8* __restrict__ xq,
                          int n8, const unsigned int* __restrict__ sa_bits) {
  int i = blockIdx.x * blockDim.x + threadIdx.x;
  if (i >= n8) return;
  float s_a = __uint_as_float(*sa_bits) / 127.0f;
  const float4* p = (const float4*)(x + (size_t)i * 8);
  float4 v0 = p[0], v1 = p[1];
  float vv[8] = {v0.x, v0.y, v0.z, v0.w, v1.x, v1.y, v1.z, v1.w};
  c8 q;
#pragma unroll
  for (int j = 0; j < 8; ++j) {
    float r = fminf(fmaxf(rintf(vv[j] / s_a), -127.f), 127.f);
    q[j] = (char)(int)r;
  }
  xq[i] = q;
}

// ---- kernel 3: per-row weight absmax + quantize (1 block / row) ----
__global__ __launch_bounds__(256) void k_quant_w(const float* __restrict__ w,
                                                 c8* __restrict__ wq,
                                                 float* __restrict__ s_w) {
  int row = blockIdx.x;
  int tid = threadIdx.x;
  const float4* wr = (const float4*)(w + (size_t)row * DIN);
  float4 v0 = wr[tid * 2], v1 = wr[tid * 2 + 1];
  float vv[8] = {v0.x, v0.y, v0.z, v0.w, v1.x, v1.y, v1.z, v1.w};
  float m = 0.f;
#pragma unroll
  for (int j = 0; j < 8; ++j) m = fmaxf(m, fabsf(vv[j]));
  m = wave_max(m);
  __shared__ float wmax[4];
  if ((tid & 63) == 0) wmax[tid >> 6] = m;
  __syncthreads();
  m = fmaxf(fmaxf(wmax[0], wmax[1]), fmaxf(wmax[2], wmax[3]));
  float s = m / 127.0f;
  if (tid == 0) s_w[row] = s;
  c8 q;
#pragma unroll
  for (int j = 0; j < 8; ++j) {
    float r = fminf(fmaxf(rintf(vv[j] / s), -127.f), 127.f);
    q[j] = (char)(int)r;
  }
  wq[(size_t)row * (DIN / 8) + tid] = q;
}

// ---- kernel 4: int8 GEMM, 256x128 tile, 4 waves, 48KB LDS -> 2 blocks/CU --
// Geometry rationale (R12-R15): registers bind occupancy (acc 128 + arch
// ~108 = 236/wave -> 2 waves/SIMD); an 8-wave 256^2 block is ALWAYS alone on
// its CU, so its stage/drain path (R12 ablation: ~60% of time) is naked.
// This kernel keeps per-wave intensity (128x64 out/wave, same acc) but packs
// it as 4-wave blocks: 48KB LDS, 2 blocks/CU = same 8 waves/CU, now in two
// INDEPENDENT blocks -> one block's m97-style convoy (sync;stage;sync;MFMA)
// overlaps the other's compute (m114 mechanism; m97 was single-buffered and
// won exactly this way at 3 blocks/CU).
// LDS (48KB): A [ks(2)][16KB] at 0, B [ks(2)][8KB] at 32768; region layout
// [rblk][kg4][fr16] 16B cells -> frag ds_read = 64 lanes x consecutive 1024B
// (0 conflicts, verified R5+); staging dst collapses to base + tid*16.
__global__ __launch_bounds__(256) void k_gemm4(
    const char* __restrict__ Aq, const char* __restrict__ Bq,
    const float* __restrict__ s_w, const float* __restrict__ bias,
    const unsigned int* __restrict__ sa_bits, float* __restrict__ out,
    unsigned int* __restrict__ omax_bits) {
  __shared__ __align__(16) char lds[49152];

  const int tid = threadIdx.x;
  const int lane = tid & 63;
  const int wave = tid >> 6;  // 0..3
  const int wm = wave >> 1;   // 0..1 (M half: 128 rows)
  const int wn = wave & 1;    // 0..1 (N half: 64 cols)

  // bijective 2D XCD-patch swizzle over the 32(by) x 64(bx) grid:
  // XCDs tiled 2(by) x 4(bx); each XCD owns a 16x16 patch.
  const int orig = blockIdx.x;
  const int xcd = orig & 7;
  const int k = orig >> 3;  // 0..255
  const int by = (xcd >> 2) * 16 + (k & 15);  // 0..31
  const int bx = (xcd & 3) * 16 + (k >> 4);   // 0..63
  const int row0 = by * 256, col0 = bx * 128;

  // staging source mapping: thread t covers cell
  // (rblk_local=t>>6, kg=(t>>4)&3, fr=t&15) of a 64-row group:
  // row = g*64 + (t>>6)*16 + (t&15), kbyte = t&48; dst = base + g*4096 + t*16.
  const int sr = ((tid >> 6) << 4) | (tid & 15);
  const int skb = tid & 48;
  const char* aS = Aq + (size_t)(row0 + sr) * DIN + skb;
  const char* bS = Bq + (size_t)(col0 + sr) * DIN + skb;

  v4i acc[2][4][4];  // [mh][mf][nf]
#pragma unroll
  for (int mh = 0; mh < 2; ++mh)
#pragma unroll
    for (int mf = 0; mf < 4; ++mf)
#pragma unroll
      for (int nf = 0; nf < 4; ++nf) acc[mh][mf][nf] = (v4i){0, 0, 0, 0};

  const int lb = lane * 16;

#pragma unroll 1
  for (int kt = 0; kt < NKT; ++kt) {
    __syncthreads();  // all waves done reading tile kt-1
    const size_t ko = (size_t)kt * 128;
#pragma unroll
    for (int ks = 0; ks < 2; ++ks) {
      // A: 256 rows = 4 groups of 64
#pragma unroll
      for (int g = 0; g < 4; ++g)
        gload_lds16(aS + (size_t)g * 64 * DIN + ko + ks * 64,
                    &lds[ks * 16384 + g * 4096 + tid * 16]);
      // B: 128 rows = 2 groups of 64
#pragma unroll
      for (int g = 0; g < 2; ++g)
        gload_lds16(bS + (size_t)g * 64 * DIN + ko + ks * 64,
                    &lds[32768 + ks * 8192 + g * 4096 + tid * 16]);
    }
    __syncthreads();  // compiler drains vmcnt(0) before barrier -> resident

#pragma unroll
    for (int ks = 0; ks < 2; ++ks) {
      v4i b_[4];
      const int bb = 32768 + ks * 8192 + (wn * 4) * 1024 + lb;
#pragma unroll
      for (int nf = 0; nf < 4; ++nf) b_[nf] = *(const v4i*)&lds[bb + nf * 1024];
#pragma unroll
      for (int mh = 0; mh < 2; ++mh) {
        v4i a_[4];
        const int ab = ks * 16384 + (wm * 8 + mh * 4) * 1024 + lb;
#pragma unroll
        for (int mf = 0; mf < 4; ++mf)
          a_[mf] = *(const v4i*)&lds[ab + mf * 1024];
#pragma unroll
        for (int nf = 0; nf < 4; ++nf)
#pragma unroll
          for (int mf = 0; mf < 4; ++mf)
            acc[mh][mf][nf] = __builtin_amdgcn_mfma_i32_16x16x64_i8(
                a_[mf], b_[nf], acc[mh][mf][nf], 0, 0, 0);
      }
    }
  }

  // epilogue: out = (acc + round(bias/s_b)) * s_b, s_b = s_w[col]*s_a
  const int fr = lane & 15;
  float s_a = __uint_as_float(*sa_bits) / 127.0f;
  float lmax = 0.f;
#pragma unroll
  for (int nf = 0; nf < 4; ++nf) {
    int col = col0 + wn * 64 + nf * 16 + fr;
    float sw = s_w[col];
    float sb = sw * s_a;
    float bint = rintf(bias[col] / sb);
#pragma unroll
    for (int mh = 0; mh < 2; ++mh)
#pragma unroll
      for (int mf = 0; mf < 4; ++mf) {
        int rbase = row0 + wm * 128 + mh * 64 + mf * 16 + (lane >> 4) * 4;
#pragma unroll
        for (int r = 0; r < 4; ++r) {
          float o = ((float)acc[mh][mf][nf][r] + bint) * sb;
          out[(size_t)(rbase + r) * DOUT + col] = o;
          lmax = fmaxf(lmax, fabsf(o));
        }
      }
  }
  // block-level max reduce -> 1 atomic per block
  lmax = wave_max(lmax);
  __syncthreads();
  float* red = (float*)lds;
  if (lane == 0) red[wave] = lmax;
  __syncthreads();
  if (tid == 0) {
    float m = fmaxf(fmaxf(red[0], red[1]), fmaxf(red[2], red[3]));
    atomicMax(omax_bits, __float_as_uint(m));
  }
}

// ---- kernel 5: requantize output in place ----
__global__ void k_requant(float4* __restrict__ out, int n4,
                          const unsigned int* __restrict__ omax_bits) {
  float s_o = __uint_as_float(*omax_bits) / 127.0f;
  int idx = blockIdx.x * blockDim.x + threadIdx.x;
  int stride = gridDim.x * blockDim.x;
  for (int i = idx; i < n4; i += stride) {
    float4 v = out[i];
    v.x = fminf(fmaxf(rintf(v.x / s_o), -127.f), 127.f) * s_o;
    v.y = fminf(fmaxf(rintf(v.y / s_o), -127.f), 127.f) * s_o;
    v.z = fminf(fmaxf(rintf(v.z / s_o), -127.f), 127.f) * s_o;
    v.w = fminf(fmaxf(rintf(v.w / s_o), -127.f), 127.f) * s_o;
    out[i] = v;
  }
}

extern "C" void kernel_launch(void* const* d_in, const int* in_sizes, int n_in,
                              void* d_out, int out_size, void* d_ws,
                              size_t ws_size, hipStream_t stream) {
  const float* x = (const float*)d_in[0];
  const float* w = (const float*)d_in[1];
  const float* bias = (const float*)d_in[2];
  float* out = (float*)d_out;
  char* ws = (char*)d_ws;

  unsigned int* absbits = (unsigned int*)ws;
  float* s_w = (float*)(ws + 512);
  char* xq = ws + 65536;
  char* wq = ws + 65536 + (size_t)B_DIM * DIN;

  k_init<<<1, 1, 0, stream>>>(absbits);
  k_absmax<<<1024, 256, 0, stream>>>((const float4*)x, B_DIM * DIN / 4, absbits);
  k_quant_x<<<(B_DIM * DIN / 8) / 256, 256, 0, stream>>>(x, (c8*)xq,
                                                         B_DIM * DIN / 8, absbits);
  k_quant_w<<<DOUT, 256, 0, stream>>>(w, (c8*)wq, s_w);
  k_gemm4<<<2048, 256, 0, stream>>>(xq, wq, s_w, bias, absbits, out, absbits + 1);
  k_requant<<<4096, 256, 0, stream>>>((float4*)out, B_DIM * DOUT / 4, absbits + 1);
}

// Round 17
// 314.348 us; speedup vs baseline: 1.8029x; 1.8029x over previous
//
#include <hip/hip_runtime.h>
#include <stdint.h>

#define B_DIM 8192
#define DIN   2048
#define DOUT  8192
#define NKT   (DIN / 128)  // 16 K-tiles of 128 bytes

typedef int  v4i __attribute__((ext_vector_type(4)));
typedef char c8  __attribute__((ext_vector_type(8)));

__device__ __forceinline__ void gload_lds16(const void* g, void* l) {
  __builtin_amdgcn_global_load_lds(
      (const __attribute__((address_space(1))) void*)g,
      (__attribute__((address_space(3))) void*)l, 16, 0, 0);
}

__device__ __forceinline__ float wave_max(float m) {
#pragma unroll
  for (int off = 32; off; off >>= 1) m = fmaxf(m, __shfl_xor(m, off, 64));
  return m;
}

// ---- kernel 0: zero the two atomic absmax words ----
__global__ void k_init(unsigned int* p) {
  p[0] = 0u;
  p[1] = 0u;
}

// ---- kernel 1: global absmax of x (block-reduced, 1 atomic/block) ----
__global__ __launch_bounds__(256) void k_absmax(const float4* __restrict__ x,
                                                int n4,
                                                unsigned int* __restrict__ out_bits) {
  int idx = blockIdx.x * blockDim.x + threadIdx.x;
  int stride = gridDim.x * blockDim.x;
  float m = 0.f;
  for (int i = idx; i < n4; i += stride) {
    float4 v = x[i];
    m = fmaxf(m, fabsf(v.x));
    m = fmaxf(m, fabsf(v.y));
    m = fmaxf(m, fabsf(v.z));
    m = fmaxf(m, fabsf(v.w));
  }
  m = wave_max(m);
  __shared__ float red[4];
  if ((threadIdx.x & 63) == 0) red[threadIdx.x >> 6] = m;
  __syncthreads();
  if (threadIdx.x == 0) {
    m = fmaxf(fmaxf(red[0], red[1]), fmaxf(red[2], red[3]));
    atomicMax(out_bits, __float_as_uint(m));
  }
}

// ---- kernel 2: quantize x to int8 (8 elems/thread) ----
__global__ void k_quant_x(const float* __restrict__ x, c8* __restrict__ xq,
                          int n8, const unsigned int* __restrict__ sa_bits) {
  int i = blockIdx.x * blockDim.x + threadIdx.x;
  if (i >= n8) return;
  float s_a = __uint_as_float(*sa_bits) / 127.0f;
  const float4* p = (const float4*)(x + (size_t)i * 8);
  float4 v0 = p[0], v1 = p[1];
  float vv[8] = {v0.x, v0.y, v0.z, v0.w, v1.x, v1.y, v1.z, v1.w};
  c8 q;
#pragma unroll
  for (int j = 0; j < 8; ++j) {
    float r = fminf(fmaxf(rintf(vv[j] / s_a), -127.f), 127.f);
    q[j] = (char)(int)r;
  }
  xq[i] = q;
}

// ---- kernel 3: per-row weight absmax + quantize (1 block / row) ----
__global__ __launch_bounds__(256) void k_quant_w(const float* __restrict__ w,
                                                 c8* __restrict__ wq,
                                                 float* __restrict__ s_w) {
  int row = blockIdx.x;
  int tid = threadIdx.x;
  const float4* wr = (const float4*)(w + (size_t)row * DIN);
  float4 v0 = wr[tid * 2], v1 = wr[tid * 2 + 1];
  float vv[8] = {v0.x, v0.y, v0.z, v0.w, v1.x, v1.y, v1.z, v1.w};
  float m = 0.f;
#pragma unroll
  for (int j = 0; j < 8; ++j) m = fmaxf(m, fabsf(vv[j]));
  m = wave_max(m);
  __shared__ float wmax[4];
  if ((tid & 63) == 0) wmax[tid >> 6] = m;
  __syncthreads();
  m = fmaxf(fmaxf(wmax[0], wmax[1]), fmaxf(wmax[2], wmax[3]));
  float s = m / 127.0f;
  if (tid == 0) s_w[row] = s;
  c8 q;
#pragma unroll
  for (int j = 0; j < 8; ++j) {
    float r = fminf(fmaxf(rintf(vv[j] / s), -127.f), 127.f);
    q[j] = (char)(int)r;
  }
  wq[(size_t)row * (DIN / 8) + tid] = q;
}

// ---- kernel 4: int8 GEMM 256x256, 8-phase, FULL-LINE staging + XOR swizzle -
// R16 diagnosis: fragment-linear LDS forced 64B DMA source segments; measured
// DMA-LDS throughput 8 B/cyc/CU vs m201's 18.5 (full 128B lines). This is the
// m201-faithful byte pattern: LDS row-major [256 rows][128B] per operand per
// slot, slot-XOR swizzle (16B slot ^= row&7); gload dst linear (rule #21:
// pre-swizzled SOURCE + swizzled READ, same involution). Source segments are
// perfect 128B-aligned lines (8 rows x 128B per gload instruction).
// ds_read bank audit: lane l (fr=l&15, kg=l>>4): addr = row*128 +
// 16*((ks*4+kg)^(fr&7)); per 4-bank group exactly 8 lanes -> even 8-beat
// schedule (~2-way = free, m136).
// Units: (op, quarter q = 64 rows) = 8KB = 1 gload. Calendar (tile t, phases
// p1..p4 = ks0mh0, ks0mh1, ks1mh0, ks1mh1; stage 2 units/phase):
//   p1: A q1,q3 (t+1)   p2: B q0,q2 (t+1)   p3: B q1,q3 (t+1)
//   p4: A q0,q2 (t+2)
// WAR audit: wave (wm,wn) reads A-quarter (2wm+mh) only at mh-phases, B
// quarter wn every phase. A q1,q3(t+1)@p1 overwrites t-1's (last read
// (t-1,p4), 1 barrier); B(t+1)@p2/p3 overwrites t-1's (last read (t-1,p4));
// A q0,q2(t+2)@p4 overwrites t's mh0 quarters (last read p3, 1 barrier).
// Residency: every unit staged 2-5 phases before first read; uniform
// vmcnt(2)/phase confirms all issues >=1 phase old => reads always touch
// confirmed data. Tails: kt>=NKT -> last same-parity tile (idempotent bytes).
__global__ __launch_bounds__(512) void k_gemm8(
    const char* __restrict__ Aq, const char* __restrict__ Bq,
    const float* __restrict__ s_w, const float* __restrict__ bias,
    const unsigned int* __restrict__ sa_bits, float* __restrict__ out,
    unsigned int* __restrict__ omax_bits) {
  __shared__ __align__(16) char lds[131072];

  const int tid = threadIdx.x;
  const int lane = tid & 63;
  const int wave = tid >> 6;
  const int wm = wave >> 2;  // 0..1 (M)
  const int wn = wave & 3;   // 0..3 (N)

  // bijective 2D L2-patch swizzle (R4-verified: FETCH 271->99 MB)
  const int orig = blockIdx.x;
  const int xcd = orig & 7;
  const int k = orig >> 3;
  const int bx = (xcd & 3) * 8 + (k & 7);
  const int by = (xcd >> 2) * 16 + (k >> 3);
  const int row0 = by * 256, col0 = bx * 256;

  // staging: thread t covers row_local = t>>3 (64 rows/gload), 16B slot t&7;
  // source slot pre-swizzled: global kbyte = 16*((t&7)^((t>>3)&7)).
  const size_t srcOff =
      (size_t)(tid >> 3) * DIN + 16 * ((tid & 7) ^ ((tid >> 3) & 7));
  const char* aS = Aq + (size_t)row0 * DIN + srcOff;
  const char* bS = Bq + (size_t)col0 * DIN + srcOff;

  // stage one (op, quarter) unit of K-tile kt (1 gload, 8KB)
  auto STAGE1 = [&](int kt, int isB, int q) {
    if (kt >= NKT) kt = NKT - 2 + (kt & 1);  // tail: last same-parity tile
    const int slot = kt & 1;
    const char* src = (isB ? bS : aS) + (size_t)(q * 64) * DIN + (size_t)kt * 128;
    gload_lds16(src, &lds[slot * 65536 + isB * 32768 + q * 8192 + tid * 16]);
  };

  v4i acc[2][4][4];
#pragma unroll
  for (int mh = 0; mh < 2; ++mh)
#pragma unroll
    for (int mf = 0; mf < 4; ++mf)
#pragma unroll
      for (int nf = 0; nf < 4; ++nf) acc[mh][mf][nf] = (v4i){0, 0, 0, 0};

  const int fr = lane & 15;
  const int kg = lane >> 4;
  // swizzled lane part (ks=0): row-in-frag byte + 16*(kg ^ (fr&7)).
  // ks=1 flips bit 6 (slot^4): addr ^ 64.
  const int lp = fr * 128 + 16 * (kg ^ (fr & 7));
  v4i b_[4];  // persists across the (mh0, mh1) phase pair

#define PH(SLOT, KS, MH, SKT, SISB, SQA, SQB)                                \
  do {                                                                       \
    v4i a_[4];                                                               \
    const int ab = (SLOT) * 65536 + wm * 16384 + (MH) * 8192 + lp;           \
    const int bb = (SLOT) * 65536 + 32768 + wn * 8192 + lp;                  \
    if (!(MH)) b_[0] = *(const v4i*)&lds[bb ^ ((KS) * 64)];                  \
    _Pragma("unroll") for (int mf = 0; mf < 4; ++mf) a_[mf] =                \
        *(const v4i*)&lds[(ab + mf * 2048) ^ ((KS) * 64)];                   \
    if (!(MH)) {                                                             \
      _Pragma("unroll") for (int nf = 1; nf < 4; ++nf) b_[nf] =              \
          *(const v4i*)&lds[(bb + nf * 2048) ^ ((KS) * 64)];                 \
    }                                                                        \
    STAGE1(SKT, SISB, SQA);                                                  \
    STAGE1(SKT, SISB, SQB);                                                  \
    asm volatile("s_waitcnt vmcnt(2)" ::: "memory");                         \
    _Pragma("unroll") for (int nf = 0; nf < 4; ++nf)                         \
        _Pragma("unroll") for (int mf = 0; mf < 4; ++mf) acc[MH][mf][nf] =   \
        __builtin_amdgcn_mfma_i32_16x16x64_i8(a_[mf], b_[nf],                \
                                              acc[MH][mf][nf], 0, 0, 0);     \
    __builtin_amdgcn_s_barrier();                                            \
  } while (0)

  // prologue: tile0 fully (8 units) + A q0,q2 of tile1; vmcnt(2) leaves the
  // tile1 pair outstanding (confirmed at (0,p1)'s wait, read at (1,p1)).
  STAGE1(0, 0, 0);
  STAGE1(0, 0, 2);
  STAGE1(0, 0, 1);
  STAGE1(0, 0, 3);
  STAGE1(0, 1, 0);
  STAGE1(0, 1, 2);
  STAGE1(0, 1, 1);
  STAGE1(0, 1, 3);
  STAGE1(1, 0, 0);
  STAGE1(1, 0, 2);
  asm volatile("s_waitcnt vmcnt(2)" ::: "memory");
  __builtin_amdgcn_s_barrier();

#pragma unroll 1
  for (int i = 0; i < NKT / 2; ++i) {
    const int t1 = 2 * i + 1, t2 = 2 * i + 2, t3 = 2 * i + 3;
    // tile 2i (slot 0)
    PH(0, 0, 0, t1, 0, 1, 3);  // p1: A q1,q3 (t+1)
    PH(0, 0, 1, t1, 1, 0, 2);  // p2: B q0,q2 (t+1)
    PH(0, 1, 0, t1, 1, 1, 3);  // p3: B q1,q3 (t+1)
    PH(0, 1, 1, t2, 0, 0, 2);  // p4: A q0,q2 (t+2)
    // tile 2i+1 (slot 1)
    PH(1, 0, 0, t2, 0, 1, 3);
    PH(1, 0, 1, t2, 1, 0, 2);
    PH(1, 1, 0, t2, 1, 1, 3);
    PH(1, 1, 1, t3, 0, 0, 2);
  }
#undef PH

  // epilogue: out = (acc + round(bias/s_b)) * s_b, s_b = s_w[col]*s_a
  float s_a = __uint_as_float(*sa_bits) / 127.0f;
  float lmax = 0.f;
#pragma unroll
  for (int nf = 0; nf < 4; ++nf) {
    int col = col0 + wn * 64 + nf * 16 + fr;
    float sw = s_w[col];
    float sb = sw * s_a;
    float bint = rintf(bias[col] / sb);
#pragma unroll
    for (int mh = 0; mh < 2; ++mh)
#pragma unroll
      for (int mf = 0; mf < 4; ++mf) {
        int rbase = row0 + wm * 128 + mh * 64 + mf * 16 + (lane >> 4) * 4;
#pragma unroll
        for (int r = 0; r < 4; ++r) {
          float o = ((float)acc[mh][mf][nf][r] + bint) * sb;
          out[(size_t)(rbase + r) * DOUT + col] = o;
          lmax = fmaxf(lmax, fabsf(o));
        }
      }
  }
  // block-level max reduce -> 1 atomic per block
  lmax = wave_max(lmax);
  asm volatile("s_waitcnt vmcnt(0)" ::: "memory");  // drain tail DMA into LDS
  __syncthreads();
  float* red = (float*)lds;
  if (lane == 0) red[wave] = lmax;
  __syncthreads();
  if (tid == 0) {
    float m = 0.f;
#pragma unroll
    for (int w2 = 0; w2 < 8; ++w2) m = fmaxf(m, red[w2]);
    atomicMax(omax_bits, __float_as_uint(m));
  }
}

// ---- kernel 5: requantize output in place ----
__global__ void k_requant(float4* __restrict__ out, int n4,
                          const unsigned int* __restrict__ omax_bits) {
  float s_o = __uint_as_float(*omax_bits) / 127.0f;
  int idx = blockIdx.x * blockDim.x + threadIdx.x;
  int stride = gridDim.x * blockDim.x;
  for (int i = idx; i < n4; i += stride) {
    float4 v = out[i];
    v.x = fminf(fmaxf(rintf(v.x / s_o), -127.f), 127.f) * s_o;
    v.y = fminf(fmaxf(rintf(v.y / s_o), -127.f), 127.f) * s_o;
    v.z = fminf(fmaxf(rintf(v.z / s_o), -127.f), 127.f) * s_o;
    v.w = fminf(fmaxf(rintf(v.w / s_o), -127.f), 127.f) * s_o;
    out[i] = v;
  }
}

extern "C" void kernel_launch(void* const* d_in, const int* in_sizes, int n_in,
                              void* d_out, int out_size, void* d_ws,
                              size_t ws_size, hipStream_t stream) {
  const float* x = (const float*)d_in[0];
  const float* w = (const float*)d_in[1];
  const float* bias = (const float*)d_in[2];
  float* out = (float*)d_out;
  char* ws = (char*)d_ws;

  unsigned int* absbits = (unsigned int*)ws;
  float* s_w = (float*)(ws + 512);
  char* xq = ws + 65536;
  char* wq = ws + 65536 + (size_t)B_DIM * DIN;

  k_init<<<1, 1, 0, stream>>>(absbits);
  k_absmax<<<1024, 256, 0, stream>>>((const float4*)x, B_DIM * DIN / 4, absbits);
  k_quant_x<<<(B_DIM * DIN / 8) / 256, 256, 0, stream>>>(x, (c8*)xq,
                                                         B_DIM * DIN / 8, absbits);
  k_quant_w<<<DOUT, 256, 0, stream>>>(w, (c8*)wq, s_w);
  k_gemm8<<<1024, 512, 0, stream>>>(xq, wq, s_w, bias, absbits, out, absbits + 1);
  k_requant<<<4096, 256, 0, stream>>>((float4*)out, B_DIM * DOUT / 4, absbits + 1);
}

// Round 18
// 303.613 us; speedup vs baseline: 1.8666x; 1.0354x over previous
//
#include <hip/hip_runtime.h>
#include <stdint.h>

#define B_DIM 8192
#define DIN   2048
#define DOUT  8192
#define NKT   (DIN / 128)  // 16 K-tiles of 128 bytes

typedef int  v4i __attribute__((ext_vector_type(4)));
typedef char c8  __attribute__((ext_vector_type(8)));

__device__ __forceinline__ void gload_lds16(const void* g, void* l) {
  __builtin_amdgcn_global_load_lds(
      (const __attribute__((address_space(1))) void*)g,
      (__attribute__((address_space(3))) void*)l, 16, 0, 0);
}

__device__ __forceinline__ float wave_max(float m) {
#pragma unroll
  for (int off = 32; off; off >>= 1) m = fmaxf(m, __shfl_xor(m, off, 64));
  return m;
}

// ---- kernel 0: zero the two atomic absmax words ----
__global__ void k_init(unsigned int* p) {
  p[0] = 0u;
  p[1] = 0u;
}

// ---- kernel 1: global absmax of x (block-reduced, 1 atomic/block) ----
__global__ __launch_bounds__(256) void k_absmax(const float4* __restrict__ x,
                                                int n4,
                                                unsigned int* __restrict__ out_bits) {
  int idx = blockIdx.x * blockDim.x + threadIdx.x;
  int stride = gridDim.x * blockDim.x;
  float m = 0.f;
  for (int i = idx; i < n4; i += stride) {
    float4 v = x[i];
    m = fmaxf(m, fabsf(v.x));
    m = fmaxf(m, fabsf(v.y));
    m = fmaxf(m, fabsf(v.z));
    m = fmaxf(m, fabsf(v.w));
  }
  m = wave_max(m);
  __shared__ float red[4];
  if ((threadIdx.x & 63) == 0) red[threadIdx.x >> 6] = m;
  __syncthreads();
  if (threadIdx.x == 0) {
    m = fmaxf(fmaxf(red[0], red[1]), fmaxf(red[2], red[3]));
    atomicMax(out_bits, __float_as_uint(m));
  }
}

// ---- kernel 2: quantize x to int8 (8 elems/thread) ----
__global__ void k_quant_x(const float* __restrict__ x, c8* __restrict__ xq,
                          int n8, const unsigned int* __restrict__ sa_bits) {
  int i = blockIdx.x * blockDim.x + threadIdx.x;
  if (i >= n8) return;
  float s_a = __uint_as_float(*sa_bits) / 127.0f;
  const float4* p = (const float4*)(x + (size_t)i * 8);
  float4 v0 = p[0], v1 = p[1];
  float vv[8] = {v0.x, v0.y, v0.z, v0.w, v1.x, v1.y, v1.z, v1.w};
  c8 q;
#pragma unroll
  for (int j = 0; j < 8; ++j) {
    float r = fminf(fmaxf(rintf(vv[j] / s_a), -127.f), 127.f);
    q[j] = (char)(int)r;
  }
  xq[i] = q;
}

// ---- kernel 3: per-row weight absmax + quantize (1 block / row) ----
__global__ __launch_bounds__(256) void k_quant_w(const float* __restrict__ w,
                                                 c8* __restrict__ wq,
                                                 float* __restrict__ s_w) {
  int row = blockIdx.x;
  int tid = threadIdx.x;
  const float4* wr = (const float4*)(w + (size_t)row * DIN);
  float4 v0 = wr[tid * 2], v1 = wr[tid * 2 + 1];
  float vv[8] = {v0.x, v0.y, v0.z, v0.w, v1.x, v1.y, v1.z, v1.w};
  float m = 0.f;
#pragma unroll
  for (int j = 0; j < 8; ++j) m = fmaxf(m, fabsf(vv[j]));
  m = wave_max(m);
  __shared__ float wmax[4];
  if ((tid & 63) == 0) wmax[tid >> 6] = m;
  __syncthreads();
  m = fmaxf(fmaxf(wmax[0], wmax[1]), fmaxf(wmax[2], wmax[3]));
  float s = m / 127.0f;
  if (tid == 0) s_w[row] = s;
  c8 q;
#pragma unroll
  for (int j = 0; j < 8; ++j) {
    float r = fminf(fmaxf(rintf(vv[j] / s), -127.f), 127.f);
    q[j] = (char)(int)r;
  }
  wq[(size_t)row * (DIN / 8) + tid] = q;
}

// ---- kernel 4: int8 GEMM 256x256, full-line staging, 2-PHASE DMA PIPELINE -
// R17 (164us, MfmaUtil 36%) closed the ledger: phase == DMA-bound at ~10.7
// B/cyc/CU with MFMA hidden inside. This round deepens the DMA pipeline from
// 1 phase (vmcnt(2)) to 2 phases (vmcnt(4)) to separate depth-limit from
// throughput-limit. Memory map/read addressing identical to R17 (verified):
// LDS row-major [256][128B]/operand/slot, 16B-slot XOR swizzle (slot^=row&7),
// pre-swizzled SOURCE + swizzled READ (rule #21); full 128B-line DMA sources.
// Units: (op, quarter q=64 rows) = 8KB = 1 gload/thread.
// Calendar (tau = current tile; stages issued at PHASE TOP, before reads):
//   p1: B q2,q3(tau+1)   p2: A q0,q2(tau+1)   p3: A q1,q3(tau+1)
//   p4: B q0,q1(tau+2)
// Lead audit (stage at q -> confirmed by wait at q+2 + barrier -> read >=q+3):
//   B q2,q3: staged p1, first read (tau+1,p1) = +4 | A q0,q2: p2, read +3 |
//   A q1,q3: p3, read +3 | B q0,q1: p4, read +5.  All >=3 (vmcnt(4) = 2
//   phases x 2 units/phase in flight; FIFO confirm order == issue order).
// WAR audit (restage >=1 barrier after region's last read, slot parity 2):
//   B q2,q3(tau+1) overwrites (tau-1)'s, last read (tau-1,p3) = -2 phases;
//   A q0,q2(tau+1) over (tau-1)'s, last read (tau-1,p3) = -3; A q1,q3 over
//   (tau-1)'s, last read (tau-1,p4) = -3; B q0,q1(tau+2) over (tau)'s, last
//   read (tau,p3) = -1. Reads can hoist at most to just above the q+2 wait
//   (memory-clobbered asm) -- still after their units' confirmation.
// Tails: kt>=NKT -> NKT-2+(kt&1): same slot, identical bytes (idempotent).
__global__ __launch_bounds__(512) void k_gemm8(
    const char* __restrict__ Aq, const char* __restrict__ Bq,
    const float* __restrict__ s_w, const float* __restrict__ bias,
    const unsigned int* __restrict__ sa_bits, float* __restrict__ out,
    unsigned int* __restrict__ omax_bits) {
  __shared__ __align__(16) char lds[131072];

  const int tid = threadIdx.x;
  const int lane = tid & 63;
  const int wave = tid >> 6;
  const int wm = wave >> 2;  // 0..1 (M)
  const int wn = wave & 3;   // 0..3 (N)

  // bijective 2D L2-patch swizzle (R4-verified: FETCH 271->99 MB)
  const int orig = blockIdx.x;
  const int xcd = orig & 7;
  const int k = orig >> 3;
  const int bx = (xcd & 3) * 8 + (k & 7);
  const int by = (xcd >> 2) * 16 + (k >> 3);
  const int row0 = by * 256, col0 = bx * 256;

  // staging: thread t covers row_local = t>>3 (64 rows/gload), 16B slot t&7;
  // source slot pre-swizzled: global kbyte = 16*((t&7)^((t>>3)&7)).
  const size_t srcOff =
      (size_t)(tid >> 3) * DIN + 16 * ((tid & 7) ^ ((tid >> 3) & 7));
  const char* aS = Aq + (size_t)row0 * DIN + srcOff;
  const char* bS = Bq + (size_t)col0 * DIN + srcOff;

  // stage one (op, quarter) unit of K-tile kt (1 gload, 8KB)
  auto STAGE1 = [&](int kt, int isB, int q) {
    if (kt >= NKT) kt = NKT - 2 + (kt & 1);  // tail: last same-parity tile
    const int slot = kt & 1;
    const char* src = (isB ? bS : aS) + (size_t)(q * 64) * DIN + (size_t)kt * 128;
    gload_lds16(src, &lds[slot * 65536 + isB * 32768 + q * 8192 + tid * 16]);
  };

  v4i acc[2][4][4];
#pragma unroll
  for (int mh = 0; mh < 2; ++mh)
#pragma unroll
    for (int mf = 0; mf < 4; ++mf)
#pragma unroll
      for (int nf = 0; nf < 4; ++nf) acc[mh][mf][nf] = (v4i){0, 0, 0, 0};

  const int fr = lane & 15;
  const int kg = lane >> 4;
  // swizzled lane part (ks=0): row-in-frag byte + 16*(kg ^ (fr&7)).
  // ks=1 flips bit 6 (slot^4): addr ^ 64.
  const int lp = fr * 128 + 16 * (kg ^ (fr & 7));
  v4i b_[4];  // persists across the (mh0, mh1) phase pair

#define PH(SLOT, KS, MH, SKT, SISB, SQA, SQB)                                \
  do {                                                                       \
    STAGE1(SKT, SISB, SQA);                                                  \
    STAGE1(SKT, SISB, SQB);                                                  \
    v4i a_[4];                                                               \
    const int ab = (SLOT) * 65536 + wm * 16384 + (MH) * 8192 + lp;           \
    const int bb = (SLOT) * 65536 + 32768 + wn * 8192 + lp;                  \
    if (!(MH)) b_[0] = *(const v4i*)&lds[bb ^ ((KS) * 64)];                  \
    _Pragma("unroll") for (int mf = 0; mf < 4; ++mf) a_[mf] =                \
        *(const v4i*)&lds[(ab + mf * 2048) ^ ((KS) * 64)];                   \
    if (!(MH)) {                                                             \
      _Pragma("unroll") for (int nf = 1; nf < 4; ++nf) b_[nf] =              \
          *(const v4i*)&lds[(bb + nf * 2048) ^ ((KS) * 64)];                 \
    }                                                                        \
    asm volatile("s_waitcnt vmcnt(4)" ::: "memory");                         \
    _Pragma("unroll") for (int nf = 0; nf < 4; ++nf)                         \
        _Pragma("unroll") for (int mf = 0; mf < 4; ++mf) acc[MH][mf][nf] =   \
        __builtin_amdgcn_mfma_i32_16x16x64_i8(a_[mf], b_[nf],                \
                                              acc[MH][mf][nf], 0, 0, 0);     \
    __builtin_amdgcn_s_barrier();                                            \
  } while (0)

  // prologue: tile0 fully (8 units) + tile1's B q0,q1 (the unit pair that
  // steady-state would have staged at (-1,p4)). vmcnt(2) confirms exactly
  // tile0's 8; tile1's pair stays in flight (confirmed by (0,p2)'s wait).
  STAGE1(0, 0, 0);
  STAGE1(0, 0, 2);
  STAGE1(0, 0, 1);
  STAGE1(0, 0, 3);
  STAGE1(0, 1, 0);
  STAGE1(0, 1, 1);
  STAGE1(0, 1, 2);
  STAGE1(0, 1, 3);
  STAGE1(1, 1, 0);
  STAGE1(1, 1, 1);
  asm volatile("s_waitcnt vmcnt(2)" ::: "memory");
  __builtin_amdgcn_s_barrier();

#pragma unroll 1
  for (int i = 0; i < NKT / 2; ++i) {
    const int t1 = 2 * i + 1, t2 = 2 * i + 2, t3 = 2 * i + 3;
    // tile 2i (slot 0)
    PH(0, 0, 0, t1, 1, 2, 3);  // p1: B q2,q3 (t1)
    PH(0, 0, 1, t1, 0, 0, 2);  // p2: A q0,q2 (t1)
    PH(0, 1, 0, t1, 0, 1, 3);  // p3: A q1,q3 (t1)
    PH(0, 1, 1, t2, 1, 0, 1);  // p4: B q0,q1 (t2)
    // tile 2i+1 (slot 1)
    PH(1, 0, 0, t2, 1, 2, 3);  // p1': B q2,q3 (t2)
    PH(1, 0, 1, t2, 0, 0, 2);  // p2': A q0,q2 (t2)
    PH(1, 1, 0, t2, 0, 1, 3);  // p3': A q1,q3 (t2)
    PH(1, 1, 1, t3, 1, 0, 1);  // p4': B q0,q1 (t3)
  }
#undef PH

  // epilogue: out = (acc + round(bias/s_b)) * s_b, s_b = s_w[col]*s_a
  float s_a = __uint_as_float(*sa_bits) / 127.0f;
  float lmax = 0.f;
#pragma unroll
  for (int nf = 0; nf < 4; ++nf) {
    int col = col0 + wn * 64 + nf * 16 + fr;
    float sw = s_w[col];
    float sb = sw * s_a;
    float bint = rintf(bias[col] / sb);
#pragma unroll
    for (int mh = 0; mh < 2; ++mh)
#pragma unroll
      for (int mf = 0; mf < 4; ++mf) {
        int rbase = row0 + wm * 128 + mh * 64 + mf * 16 + (lane >> 4) * 4;
#pragma unroll
        for (int r = 0; r < 4; ++r) {
          float o = ((float)acc[mh][mf][nf][r] + bint) * sb;
          out[(size_t)(rbase + r) * DOUT + col] = o;
          lmax = fmaxf(lmax, fabsf(o));
        }
      }
  }
  // block-level max reduce -> 1 atomic per block
  lmax = wave_max(lmax);
  asm volatile("s_waitcnt vmcnt(0)" ::: "memory");  // drain tail DMA into LDS
  __syncthreads();
  float* red = (float*)lds;
  if (lane == 0) red[wave] = lmax;
  __syncthreads();
  if (tid == 0) {
    float m = 0.f;
#pragma unroll
    for (int w2 = 0; w2 < 8; ++w2) m = fmaxf(m, red[w2]);
    atomicMax(omax_bits, __float_as_uint(m));
  }
}

// ---- kernel 5: requantize output in place ----
__global__ void k_requant(float4* __restrict__ out, int n4,
                          const unsigned int* __restrict__ omax_bits) {
  float s_o = __uint_as_float(*omax_bits) / 127.0f;
  int idx = blockIdx.x * blockDim.x + threadIdx.x;
  int stride = gridDim.x * blockDim.x;
  for (int i = idx; i < n4; i += stride) {
    float4 v = out[i];
    v.x = fminf(fmaxf(rintf(v.x / s_o), -127.f), 127.f) * s_o;
    v.y = fminf(fmaxf(rintf(v.y / s_o), -127.f), 127.f) * s_o;
    v.z = fminf(fmaxf(rintf(v.z / s_o), -127.f), 127.f) * s_o;
    v.w = fminf(fmaxf(rintf(v.w / s_o), -127.f), 127.f) * s_o;
    out[i] = v;
  }
}

extern "C" void kernel_launch(void* const* d_in, const int* in_sizes, int n_in,
                              void* d_out, int out_size, void* d_ws,
                              size_t ws_size, hipStream_t stream) {
  const float* x = (const float*)d_in[0];
  const float* w = (const float*)d_in[1];
  const float* bias = (const float*)d_in[2];
  float* out = (float*)d_out;
  char* ws = (char*)d_ws;

  unsigned int* absbits = (unsigned int*)ws;
  float* s_w = (float*)(ws + 512);
  char* xq = ws + 65536;
  char* wq = ws + 65536 + (size_t)B_DIM * DIN;

  k_init<<<1, 1, 0, stream>>>(absbits);
  k_absmax<<<1024, 256, 0, stream>>>((const float4*)x, B_DIM * DIN / 4, absbits);
  k_quant_x<<<(B_DIM * DIN / 8) / 256, 256, 0, stream>>>(x, (c8*)xq,
                                                         B_DIM * DIN / 8, absbits);
  k_quant_w<<<DOUT, 256, 0, stream>>>(w, (c8*)wq, s_w);
  k_gemm8<<<1024, 512, 0, stream>>>(xq, wq, s_w, bias, absbits, out, absbits + 1);
  k_requant<<<4096, 256, 0, stream>>>((float4*)out, B_DIM * DOUT / 4, absbits + 1);
}